// Round 8
// baseline (402.081 us; speedup 1.0000x reference)
//
#include <hip/hip_runtime.h>

#define TOK   16384   // B*T
#define DIM_  1024
#define QKV_N 3072
#define NH    16
#define HD    64
#define NF    256
#define TSEQ  4096
#define NCHUNK 8
#define CH_T  512     // TSEQ/NCHUNK
#define KVS   68      // kv row stride (64 d + 1 ksum + pad)

typedef __attribute__((ext_vector_type(8))) short  bfrag8;   // 8 bf16 (4 VGPRs)
typedef __attribute__((ext_vector_type(4))) float  ffrag4;   // 4 fp32 acc
typedef __attribute__((ext_vector_type(8))) unsigned short u16x8;
typedef __attribute__((ext_vector_type(4))) unsigned short u16x4;

__device__ __forceinline__ float bf2f(unsigned short u) {
  union { unsigned int i; float f; } c; c.i = ((unsigned int)u) << 16; return c.f;
}
__device__ __forceinline__ unsigned short f2bf(float f) {
  union { float f; unsigned int i; } c; c.f = f;
  unsigned int r = c.i + 0x7FFFu + ((c.i >> 16) & 1u);
  return (unsigned short)(r >> 16);
}

__device__ __forceinline__ void gload16(const unsigned short* g, unsigned short* l) {
  __builtin_amdgcn_global_load_lds(
      (const __attribute__((address_space(1))) unsigned int*)g,
      (__attribute__((address_space(3))) unsigned int*)l, 16, 0, 0);
}

// ---------------- batched transpose + cast fp32 [R][C] -> bf16 [C][R] ----------------
__global__ __launch_bounds__(256)
void transpose_cast(const float* __restrict__ in, unsigned short* __restrict__ out,
                    int R, int C) {
  __shared__ float tile[32][33];
  const size_t batch_off = (size_t)blockIdx.z * R * C;
  const float* bin = in + batch_off;
  unsigned short* bout = out + batch_off;
  const int bc = blockIdx.x * 32, br = blockIdx.y * 32;
  const int tx = threadIdx.x & 31, ty = threadIdx.x >> 5;   // 32x8
  #pragma unroll
  for (int i = 0; i < 32; i += 8)
    tile[ty + i][tx] = bin[(size_t)(br + ty + i) * C + bc + tx];
  __syncthreads();
  #pragma unroll
  for (int i = 0; i < 32; i += 8)
    bout[(size_t)(bc + ty + i) * R + br + tx] = f2bf(tile[tx][ty + i]);
}

// ---------------- 256x256 8-phase bf16 GEMM (T1+T2+T3+T4+T5) ----------------
// C[M][N] = A[M][K] @ BT[N][KB]^T (+bias), B K-tiles wrapped mod KB/64.
// v8: CVT path — A is fp32, cast fused into reg-staged A-path (T14 split):
//   q0/q1: ds_write A(t+1) from regs (loaded last tile) + issue fp32 loads for t+2.
//   Per-tile VMEM issues = 8 A-loads + 4 B-gload_lds = 12 -> steady vmcnt(12) at q3
//   guarantees B(t+1) landed (compiler's reg-dep waits retire older A loads early).
#define GPHASE(Q, STG, VMW)                                                        \
  {                                                                                \
    const int ab = arow + (Q) * 2048;                                              \
    bfrag8 a00 = *(const bfrag8*)&lds[b][0][ab + cA0];                             \
    bfrag8 a01 = *(const bfrag8*)&lds[b][0][ab + cA1];                             \
    bfrag8 a10 = *(const bfrag8*)&lds[b][0][ab + 1024 + cA0];                      \
    bfrag8 a11 = *(const bfrag8*)&lds[b][0][ab + 1024 + cA1];                      \
    if ((Q) == 0) {                                                                \
      _Pragma("unroll")                                                            \
      for (int j = 0; j < 4; j++) {                                                \
        bfr[j][0] = *(const bfrag8*)&lds[b][1][brow + j * 1024 + cA0];             \
        bfr[j][1] = *(const bfrag8*)&lds[b][1][brow + j * 1024 + cA1];             \
      }                                                                            \
    }                                                                              \
    STG;                                                                           \
    __builtin_amdgcn_s_barrier();                                                  \
    __builtin_amdgcn_s_setprio(1);                                                 \
    _Pragma("unroll")                                                              \
    for (int j = 0; j < 4; j++) {                                                  \
      acc[(Q)*2][j]   = __builtin_amdgcn_mfma_f32_16x16x32_bf16(a00, bfr[j][0], acc[(Q)*2][j], 0, 0, 0);   \
      acc[(Q)*2][j]   = __builtin_amdgcn_mfma_f32_16x16x32_bf16(a01, bfr[j][1], acc[(Q)*2][j], 0, 0, 0);   \
      acc[(Q)*2+1][j] = __builtin_amdgcn_mfma_f32_16x16x32_bf16(a10, bfr[j][0], acc[(Q)*2+1][j], 0, 0, 0); \
      acc[(Q)*2+1][j] = __builtin_amdgcn_mfma_f32_16x16x32_bf16(a11, bfr[j][1], acc[(Q)*2+1][j], 0, 0, 0); \
    }                                                                              \
    __builtin_amdgcn_s_setprio(0);                                                 \
    asm volatile("s_waitcnt lgkmcnt(0)" ::: "memory");                             \
    VMW;                                                                           \
    __builtin_amdgcn_s_barrier();                                                  \
  }

template<bool CVT, bool BIAS, typename OutT>
__global__ __launch_bounds__(512, 2)
void gemm256(const void* __restrict__ Avoid,
             const unsigned short* __restrict__ BT,
             const float* __restrict__ bias, OutT* __restrict__ C,
             int M, int N, int K, int KB) {
  __shared__ alignas(16) unsigned short lds[2][2][256 * 64];
  const int tid = threadIdx.x;
  const int w = tid >> 6, lane = tid & 63;
  const int wm = w >> 2, wn = w & 3;            // 2 x 4 waves
  const int lq = lane >> 4, lr = lane & 15;

  const int nbx = N >> 8;
  const int cpx = (int)gridDim.x >> 3;
  const int bid = (int)blockIdx.x;
  const int swz = (bid & 7) * cpx + (bid >> 3);
  const int m0 = (swz / nbx) << 8;
  const int n0 = (swz % nbx) << 8;
  const int nkt = K >> 6;
  const int mskB = (KB >> 6) - 1;               // power-of-two tile counts only

  const int sr = tid >> 3;
  const int sc = ((tid & 7) ^ (sr & 7)) << 3;   // element-indexed swizzled col
  const unsigned short* A16 = (const unsigned short*)Avoid;
  const float*          A32 = (const float*)Avoid;
  const unsigned short* gA = CVT ? nullptr : A16 + (size_t)(m0 + sr) * K + sc;
  const unsigned short* gB = BT + (size_t)(n0 + sr) * KB + sc;

  const int swl = (lr & 7) << 3;
  const int cA0 = (lq * 8) ^ swl;
  const int cA1 = (32 + lq * 8) ^ swl;
  const int arow = (wm * 128 + lr) * 64;
  const int brow = (wn * 64 + lr) * 64;

  ffrag4 acc[8][4] = {};
  bfrag8 bfr[4][2];

  auto stage = [&](int bb, int mat, int h, int kt) {
    const int kk = mat ? (kt & mskB) : kt;
    const int str = mat ? KB : K;
    const unsigned short* g = (mat ? gB : gA) + (size_t)(h * 128) * str + (size_t)kk * 64;
    unsigned short* l = &lds[bb][mat][h * 8192 + tid * 8];
    gload16(g, l);
    gload16(g + (size_t)64 * str, l + 4096);
  };

  // CVT A-path: 2 named reg buffers (rule #20: static indexing), 16 floats each.
  float4 bufA0[4], bufA1[4];
  auto aload = [&](int h, int kt, float4 (&bf)[4]) {
    const float* g = A32 + (size_t)(m0 + h * 128 + sr) * K + (size_t)kt * 64 + sc;
    bf[0] = *(const float4*)&g[0];
    bf[1] = *(const float4*)&g[4];
    bf[2] = *(const float4*)&g[(size_t)64 * K];
    bf[3] = *(const float4*)&g[(size_t)64 * K + 4];
  };
  auto awrite = [&](int bb, int h, const float4 (&bf)[4]) {
    const float* f = (const float*)&bf[0];
    u16x8 o0, o1;
    #pragma unroll
    for (int e = 0; e < 4; e++) {
      o0[e] = f2bf(f[e]);      o0[4 + e] = f2bf(f[4 + e]);
      o1[e] = f2bf(f[8 + e]);  o1[4 + e] = f2bf(f[12 + e]);
    }
    unsigned short* l = &lds[bb][0][h * 8192 + tid * 8];
    *(u16x8*)l = o0;
    *(u16x8*)&l[4096] = o1;
  };

  if constexpr (CVT) {
    aload(0, 0, bufA0); aload(1, 0, bufA1);    // A(0) -> regs      [8 loads]
    stage(0, 1, 0, 0);  stage(0, 1, 1, 0);     // B(0) -> buf0      [4]
    awrite(0, 0, bufA0); awrite(0, 1, bufA1);  // A(0) -> buf0 (waits its 8 loads)
    aload(0, 1, bufA0); aload(1, 1, bufA1);    // A(1) -> regs      [8]
    stage(1, 1, 0, 1);  stage(1, 1, 1, 1);     // B(1) -> buf1      [4]
    // outstanding = A(1)8 + B(1)4 = 12 -> B(0) landed; drain ds_writes
    asm volatile("s_waitcnt vmcnt(12) lgkmcnt(0)" ::: "memory");
  } else {
    stage(0, 0, 0, 0); stage(0, 0, 1, 0);
    stage(0, 1, 0, 0); stage(0, 1, 1, 0);
    stage(1, 1, 0, 1); stage(1, 1, 1, 1);
    asm volatile("s_waitcnt vmcnt(4)" ::: "memory");
  }
  __builtin_amdgcn_s_barrier();

  for (int t = 0; t < nkt; ++t) {
    const int b = t & 1;
    const int bn = b ^ 1;
    if constexpr (CVT) {
      GPHASE(0, { if (t + 1 < nkt) awrite(bn, 0, bufA0); if (t + 2 < nkt) aload(0, t + 2, bufA0); }, {})
      GPHASE(1, { if (t + 1 < nkt) awrite(bn, 1, bufA1); if (t + 2 < nkt) aload(1, t + 2, bufA1); }, {})
      GPHASE(2, { if (t + 2 < nkt) stage(b, 1, 0, t + 2); }, {})
      GPHASE(3, { if (t + 2 < nkt) stage(b, 1, 1, t + 2); },
             { if (t < nkt - 2) { asm volatile("s_waitcnt vmcnt(12)" ::: "memory"); }
               else             { asm volatile("s_waitcnt vmcnt(0)" ::: "memory"); } })
    } else {
      GPHASE(0, { if (t + 1 < nkt) stage(bn, 0, 0, t + 1); }, {})
      GPHASE(1, { if (t + 1 < nkt) stage(bn, 0, 1, t + 1); }, {})
      GPHASE(2, { if (t + 2 < nkt) stage(b, 1, 0, t + 2); }, {})
      GPHASE(3, { if (t + 2 < nkt) stage(b, 1, 1, t + 2); },
             { if (t < nkt - 2) { asm volatile("s_waitcnt vmcnt(4)" ::: "memory"); }
               else             { asm volatile("s_waitcnt vmcnt(0)" ::: "memory"); } })
    }
  }

  #pragma unroll
  for (int i = 0; i < 8; i++) {
    const int row = m0 + wm * 128 + i * 16 + lq * 4;
    #pragma unroll
    for (int j = 0; j < 4; j++) {
      const int col = n0 + wn * 64 + j * 16 + lr;
      const float bb = BIAS ? bias[col] : 0.f;
      #pragma unroll
      for (int r = 0; r < 4; r++) {
        const float val = acc[i][j][r] + bb;
        if constexpr (sizeof(OutT) == 2) C[(size_t)(row + r) * N + col] = (OutT)f2bf(val);
        else                             C[(size_t)(row + r) * N + col] = (OutT)val;
      }
    }
  }
}

// ---------- Stage A: MFMA k-feature + partial kv/ksum ----------
// V^T column-swizzle + V prefetch ping-pong; v8: K A-fragment loads hoisted
// above the vT LDS writes so their HBM latency overlaps write + Z start.
__global__ __launch_bounds__(256, 2)
void kv_mfma_kernel(const unsigned short* __restrict__ qkv,
                    const unsigned short* __restrict__ projT,  // [H][256f][64d] bf16
                    float* __restrict__ partial) {
  const int c = blockIdx.x, bh = blockIdx.y;
  const int b = bh >> 4, h = bh & 15;
  const int tid = threadIdx.x;
  const int w = tid >> 6, lane = tid & 63;
  const int lq = lane >> 4, lr = lane & 15;
  __shared__ unsigned short kp[256 * 72];   // k'  [f][t], stride 72
  __shared__ unsigned short vT[80 * 72];    // V^T [d][t] col-swizzled, stride 72
  __shared__ float wmax[64][4];

  const unsigned short* pTg = projT + (size_t)h * (NF * HD);
  bfrag8 bfgP[2][4];
  #pragma unroll
  for (int kc = 0; kc < 2; kc++)
    #pragma unroll
    for (int j = 0; j < 4; j++)
      bfgP[kc][j] = *(const bfrag8*)&pTg[(size_t)(w * 64 + j * 16 + lr) * 64 + kc * 32 + lq * 8];

  for (int idx = tid; idx < 16 * 72; idx += 256) {
    const int r = idx / 72, cc = idx % 72;
    vT[(64 + r) * 72 + cc] = (r == 0 && cc < 64) ? (unsigned short)0x3F80 : (unsigned short)0;
  }
  __syncthreads();

  ffrag4 acc2[4][5];
  #pragma unroll
  for (int i = 0; i < 4; i++)
    #pragma unroll
    for (int j = 0; j < 5; j++) acc2[i][j] = (ffrag4){0.f, 0.f, 0.f, 0.f};

  const size_t rowbase = (size_t)b * TSEQ + (size_t)c * CH_T;
  const int vd0 = (tid & 7) * 8;
  const int vsg = tid & 7;
  const int vt0 = tid >> 3;

  auto loadV = [&](int tt, u16x8 (&vr)[2]) {
    #pragma unroll
    for (int e = 0; e < 2; e++) {
      const int t = e * 32 + vt0;
      vr[e] = *(const u16x8*)&qkv[(rowbase + tt * 64 + t) * QKV_N + 2048 + h * 64 + vd0];
    }
  };

  auto subtile = [&](int tt, u16x8 (&vcur)[2], u16x8 (&vnxt)[2], bool pf) {
    const int t0 = tt * 64;
    // issue K A-fragment loads FIRST (latency overlaps vT writes + Z start)
    bfrag8 af[2][4];
    #pragma unroll
    for (int kc = 0; kc < 2; kc++)
      #pragma unroll
      for (int i = 0; i < 4; i++)
        af[kc][i] = *(const bfrag8*)&qkv[(rowbase + t0 + i * 16 + lr) * QKV_N + 1024 + h * 64 + kc * 32 + lq * 8];
    #pragma unroll
    for (int e = 0; e < 2; e++) {
      const int scol = ((e * 32 + vt0) + 8 * vsg) & 63;
      #pragma unroll
      for (int q = 0; q < 8; q++) vT[(vd0 + q) * 72 + scol] = vcur[e][q];
    }
    ffrag4 accZ[4][4];
    #pragma unroll
    for (int i = 0; i < 4; i++)
      #pragma unroll
      for (int j = 0; j < 4; j++) accZ[i][j] = (ffrag4){0.f, 0.f, 0.f, 0.f};
    #pragma unroll
    for (int kc = 0; kc < 2; kc++)
      #pragma unroll
      for (int i = 0; i < 4; i++)
        #pragma unroll
        for (int j = 0; j < 4; j++)
          accZ[i][j] = __builtin_amdgcn_mfma_f32_16x16x32_bf16(af[kc][i], bfgP[kc][j], accZ[i][j], 0, 0, 0);
    float pmx[4][4];
    #pragma unroll
    for (int i = 0; i < 4; i++)
      #pragma unroll
      for (int r = 0; r < 4; r++) {
        float m = accZ[i][0][r];
        m = fmaxf(m, accZ[i][1][r]); m = fmaxf(m, accZ[i][2][r]); m = fmaxf(m, accZ[i][3][r]);
        pmx[i][r] = m;
      }
    #pragma unroll
    for (int off = 1; off < 16; off <<= 1)
      #pragma unroll
      for (int i = 0; i < 4; i++)
        #pragma unroll
        for (int r = 0; r < 4; r++)
          pmx[i][r] = fmaxf(pmx[i][r], __shfl_xor(pmx[i][r], off, 64));
    if (lr == 0)
      #pragma unroll
      for (int i = 0; i < 4; i++)
        #pragma unroll
        for (int r = 0; r < 4; r++) wmax[i * 16 + lq * 4 + r][w] = pmx[i][r];
    __syncthreads();                               // (1) wmax + vT ready
    #pragma unroll
    for (int i = 0; i < 4; i++) {
      float rmarr[4];
      #pragma unroll
      for (int r = 0; r < 4; r++) {
        const float4 wv = *(const float4*)&wmax[i * 16 + lq * 4 + r];
        rmarr[r] = fmaxf(fmaxf(wv.x, wv.y), fmaxf(wv.z, wv.w));
      }
      #pragma unroll
      for (int j = 0; j < 4; j++) {
        u16x4 pk;
        #pragma unroll
        for (int r = 0; r < 4; r++) pk[r] = f2bf(__expf(accZ[i][j][r] - rmarr[r]));
        *(u16x4*)&kp[(w * 64 + j * 16 + lr) * 72 + i * 16 + lq * 4] = pk;
      }
    }
    if (pf) loadV(tt + 1, vnxt);                   // T14: hide under KV phase
    __syncthreads();                               // (2) kp ready
    #pragma unroll
    for (int kc = 0; kc < 2; kc++) {
      bfrag8 af2[4], bf2[5];
      #pragma unroll
      for (int i = 0; i < 4; i++)
        af2[i] = *(const bfrag8*)&kp[(w * 64 + i * 16 + lr) * 72 + kc * 32 + lq * 8];
      #pragma unroll
      for (int j = 0; j < 5; j++) {
        const int vrow = j * 16 + lr;
        const int vcol = ((kc * 32 + lq * 8) + 8 * ((2 * j + (lr >> 3)) & 7)) & 63;
        bf2[j] = *(const bfrag8*)&vT[vrow * 72 + vcol];
      }
      #pragma unroll
      for (int i = 0; i < 4; i++)
        #pragma unroll
        for (int j = 0; j < 5; j++)
          acc2[i][j] = __builtin_amdgcn_mfma_f32_16x16x32_bf16(af2[i], bf2[j], acc2[i][j], 0, 0, 0);
    }
    __syncthreads();                               // (3) protect kp/vT
  };

  u16x8 vA[2], vB[2];
  loadV(0, vA);
  for (int uu = 0; uu < CH_T / 64; uu += 2) {
    subtile(uu,     vA, vB, true);
    subtile(uu + 1, vB, vA, uu + 2 < CH_T / 64);
  }

  float* pbase = partial + (size_t)(bh * NCHUNK + c) * NF * KVS;
  #pragma unroll
  for (int i = 0; i < 4; i++)
    #pragma unroll
    for (int j = 0; j < 5; j++) {
      if (j == 4 && lr != 0) continue;
      const int col = j * 16 + lr;
      #pragma unroll
      for (int r = 0; r < 4; r++)
        pbase[(size_t)(w * 64 + i * 16 + lq * 4 + r) * KVS + col] = acc2[i][j][r];
    }
}

// ---------------- reduce kv partials over 8 chunks ----------------
__global__ __launch_bounds__(256)
void kv_reduce_kernel(const float* __restrict__ partial, float* __restrict__ kv) {
  const size_t i = (size_t)blockIdx.x * 256 + threadIdx.x;
  const size_t per_bh = (size_t)NF * KVS;
  const size_t bh = i / per_bh;
  const size_t j = i % per_bh;
  const float* p = partial + bh * NCHUNK * per_bh + j;
  float s = 0.f;
  #pragma unroll
  for (int c = 0; c < NCHUNK; c++) s += p[c * per_bh];
  kv[i] = s;
}

// ---------- Stage B: MFMA q-feature + O = q' @ [KV | ksum] + normalize ----------
// Q-fragment prefetch ping-pong; no Q-side max (cancels in the normalize ratio).
__global__ __launch_bounds__(256, 2)
void q_attn_mfma_kernel(const unsigned short* __restrict__ qkv,
                        const unsigned short* __restrict__ projT,
                        const float* __restrict__ kv,
                        unsigned short* __restrict__ attn) {
  const int c = blockIdx.x, bh = blockIdx.y;
  const int b = bh >> 4, h = bh & 15;
  const int tid = threadIdx.x;
  const int w = tid >> 6, lane = tid & 63;
  const int lq = lane >> 4, lr = lane & 15;
  __shared__ unsigned short qp[64 * 264];    // q' [t][f], stride 264
  __shared__ unsigned short kvT[80 * 264];   // KV^T [d][f] (+ksum row 64)

  {
    const float* kvrow = kv + ((size_t)bh * NF + tid) * KVS;
    #pragma unroll
    for (int d0 = 0; d0 < 64; d0 += 4) {
      const float4 v = *(const float4*)&kvrow[d0];
      kvT[(d0 + 0) * 264 + tid] = f2bf(v.x);
      kvT[(d0 + 1) * 264 + tid] = f2bf(v.y);
      kvT[(d0 + 2) * 264 + tid] = f2bf(v.z);
      kvT[(d0 + 3) * 264 + tid] = f2bf(v.w);
    }
    kvT[64 * 264 + tid] = f2bf(kvrow[64]);
    for (int idx = tid; idx < 15 * 264; idx += 256)
      kvT[65 * 264 + idx] = 0;
  }
  const unsigned short* pTg = projT + (size_t)h * (NF * HD);
  bfrag8 bfg[2][4];
  #pragma unroll
  for (int kc = 0; kc < 2; kc++)
    #pragma unroll
    for (int j = 0; j < 4; j++)
      bfg[kc][j] = *(const bfrag8*)&pTg[(size_t)(w * 64 + j * 16 + lr) * 64 + kc * 32 + lq * 8];
  __syncthreads();

  auto loadQ = [&](int tt, bfrag8 (&af)[2][4]) {
    const size_t rowb = (size_t)b * TSEQ + (size_t)c * CH_T + (size_t)tt * 64;
    #pragma unroll
    for (int kc = 0; kc < 2; kc++)
      #pragma unroll
      for (int i = 0; i < 4; i++)
        af[kc][i] = *(const bfrag8*)&qkv[(rowb + i * 16 + lr) * QKV_N + 0 + h * 64 + kc * 32 + lq * 8];
  };

  auto subtile = [&](int tt, bfrag8 (&cur)[2][4], bfrag8 (&nxt)[2][4], bool pf) {
    ffrag4 accZ[4][4];
    #pragma unroll
    for (int i = 0; i < 4; i++)
      #pragma unroll
      for (int j = 0; j < 4; j++) accZ[i][j] = (ffrag4){0.f, 0.f, 0.f, 0.f};
    #pragma unroll
    for (int kc = 0; kc < 2; kc++)
      #pragma unroll
      for (int i = 0; i < 4; i++)
        #pragma unroll
        for (int j = 0; j < 4; j++)
          accZ[i][j] = __builtin_amdgcn_mfma_f32_16x16x32_bf16(cur[kc][i], bfg[kc][j], accZ[i][j], 0, 0, 0);
    #pragma unroll
    for (int i = 0; i < 4; i++)
      #pragma unroll
      for (int j = 0; j < 4; j++)
        #pragma unroll
        for (int r = 0; r < 4; r++)
          qp[(i * 16 + lq * 4 + r) * 264 + w * 64 + j * 16 + lr] = f2bf(__expf(accZ[i][j][r]));
    if (pf) loadQ(tt + 1, nxt);                    // T14: hide under PV phase
    __syncthreads();
    ffrag4 acc3[5];
    #pragma unroll
    for (int j = 0; j < 5; j++) acc3[j] = (ffrag4){0.f, 0.f, 0.f, 0.f};
    #pragma unroll
    for (int kc = 0; kc < 8; kc++) {
      const bfrag8 afq = *(const bfrag8*)&qp[(w * 16 + lr) * 264 + kc * 32 + lq * 8];
      #pragma unroll
      for (int j = 0; j < 5; j++) {
        const bfrag8 bf3 = *(const bfrag8*)&kvT[(j * 16 + lr) * 264 + kc * 32 + lq * 8];
        acc3[j] = __builtin_amdgcn_mfma_f32_16x16x32_bf16(afq, bf3, acc3[j], 0, 0, 0);
      }
    }
    #pragma unroll
    for (int r = 0; r < 4; r++) {
      const float den = __shfl(acc3[4][r], lane & 48, 64);
      const float z = 1.f / (den + 1e-6f);
      const int t = c * CH_T + tt * 64 + w * 16 + lq * 4 + r;
      unsigned short* orow = attn + ((size_t)b * TSEQ + t) * DIM_ + h * 64;
      #pragma unroll
      for (int j = 0; j < 4; j++)
        orow[j * 16 + lr] = f2bf(acc3[j][r] * z);
    }
    __syncthreads();
  };

  bfrag8 qA[2][4], qB[2][4];
  loadQ(0, qA);
  for (int uu = 0; uu < CH_T / 64; uu += 2) {
    subtile(uu,     qA, qB, true);
    subtile(uu + 1, qB, qA, uu + 2 < CH_T / 64);
  }
}

extern "C" void kernel_launch(void* const* d_in, const int* in_sizes, int n_in,
                              void* d_out, int out_size, void* d_ws, size_t ws_size,
                              hipStream_t stream) {
  const float* x     = (const float*)d_in[0];
  const float* w_qkv = (const float*)d_in[1];
  const float* w_out = (const float*)d_in[2];
  const float* b_out = (const float*)d_in[3];
  const float* proj  = (const float*)d_in[4];
  float* out = (float*)d_out;

  char* ws = (char*)d_ws;
  // Workspace layout (max 141,295,616 B):
  //   [0,          100663296)  qkv bf16 (16384*3072)
  //   phase 1:
  //     [134217728, 140509184)  wqkvT bf16 (3072*1024)   (A comes from x directly)
  //   phase 2 (wqkvT dead after qkv GEMM):
  //     [100663296, 136314880)  partial fp32 (64*8*256*68)   — then:
  //     [100663296, 134217728)  attn bf16 (16384*1024)
  //     [134217728, 136314880)  woutT bf16 (1024*1024)
  //     [136314880, 140771328)  kv fp32 (64*256*68)
  //   [140771328, 141295616)  projT bf16 — alive throughout
  unsigned short* qkv    = (unsigned short*)ws;
  unsigned short* wqkvT  = (unsigned short*)(ws + 134217728);
  float*          partial= (float*)(ws + 100663296);
  unsigned short* attn   = (unsigned short*)(ws + 100663296);
  unsigned short* woutT  = (unsigned short*)(ws + 134217728);
  float*          kvbuf  = (float*)(ws + 136314880);
  unsigned short* projT  = (unsigned short*)(ws + 140771328);

  transpose_cast<<<dim3(QKV_N/32, DIM_/32, 1), 256, 0, stream>>>(w_qkv, wqkvT, DIM_, QKV_N);
  transpose_cast<<<dim3(NF/32, HD/32, NH), 256, 0, stream>>>(proj, projT, HD, NF);

  // 1) qkv = x @ w_qkv — bf16 GEMM, fp32->bf16 cast fused into A staging (v8)
  gemm256<true, false, unsigned short><<<768, 512, 0, stream>>>(
      (const void*)x, wqkvT, nullptr, qkv, TOK, QKV_N, 1024, 1024);
  // 2) MFMA k-feature + partial kv/ksum
  kv_mfma_kernel<<<dim3(NCHUNK, 64), 256, 0, stream>>>(qkv, projT, partial);
  // 3) reduce partials
  kv_reduce_kernel<<<dim3(64*NF*KVS/256), 256, 0, stream>>>(partial, kvbuf);
  // 4) woutT (into region freed by reduce)
  transpose_cast<<<dim3(DIM_/32, DIM_/32, 1), 256, 0, stream>>>(w_out, woutT, DIM_, DIM_);
  // 5) MFMA q-feature + q'@kv + normalize -> attn bf16
  q_attn_mfma_kernel<<<dim3(NCHUNK, 64), 256, 0, stream>>>(qkv, projT, kvbuf, attn);
  // 6) out = attn @ w_out + b_out
  gemm256<false, true, float><<<256, 512, 0, stream>>>(
      (const void*)attn, woutT, b_out, out, TOK, DIM_, DIM_, DIM_);
}

// Round 9
// 385.375 us; speedup vs baseline: 1.0433x; 1.0433x over previous
//
#include <hip/hip_runtime.h>

#define TOK   16384   // B*T
#define DIM_  1024
#define QKV_N 3072
#define NH    16
#define HD    64
#define NF    256
#define TSEQ  4096
#define NCHUNK 8
#define CH_T  512     // TSEQ/NCHUNK
#define KVS   68      // kv row stride (64 d + 1 ksum + pad)

typedef __attribute__((ext_vector_type(8))) short  bfrag8;   // 8 bf16 (4 VGPRs)
typedef __attribute__((ext_vector_type(4))) float  ffrag4;   // 4 fp32 acc
typedef __attribute__((ext_vector_type(8))) unsigned short u16x8;
typedef __attribute__((ext_vector_type(4))) unsigned short u16x4;

__device__ __forceinline__ float bf2f(unsigned short u) {
  union { unsigned int i; float f; } c; c.i = ((unsigned int)u) << 16; return c.f;
}
__device__ __forceinline__ unsigned short f2bf(float f) {
  union { float f; unsigned int i; } c; c.f = f;
  unsigned int r = c.i + 0x7FFFu + ((c.i >> 16) & 1u);
  return (unsigned short)(r >> 16);
}

__device__ __forceinline__ void gload16(const unsigned short* g, unsigned short* l) {
  __builtin_amdgcn_global_load_lds(
      (const __attribute__((address_space(1))) unsigned int*)g,
      (__attribute__((address_space(3))) unsigned int*)l, 16, 0, 0);
}

// ---------------- batched transpose + cast fp32 [R][C] -> bf16 [C][R] ----------------
__global__ __launch_bounds__(256)
void transpose_cast(const float* __restrict__ in, unsigned short* __restrict__ out,
                    int R, int C) {
  __shared__ float tile[32][33];
  const size_t batch_off = (size_t)blockIdx.z * R * C;
  const float* bin = in + batch_off;
  unsigned short* bout = out + batch_off;
  const int bc = blockIdx.x * 32, br = blockIdx.y * 32;
  const int tx = threadIdx.x & 31, ty = threadIdx.x >> 5;   // 32x8
  #pragma unroll
  for (int i = 0; i < 32; i += 8)
    tile[ty + i][tx] = bin[(size_t)(br + ty + i) * C + bc + tx];
  __syncthreads();
  #pragma unroll
  for (int i = 0; i < 32; i += 8)
    bout[(size_t)(bc + ty + i) * R + br + tx] = f2bf(tile[tx][ty + i]);
}

// ---------------- fp32 x -> bf16 (RNE) flat cast ----------------
// R9: restored as a separate pass (R8's in-GEMM fusion regressed: reg-dep waits
// + 16 f2bf + ds_write in the stage slot cost more than this 100MB stream).
__global__ __launch_bounds__(256)
void bf16_cast(const float* __restrict__ x, unsigned short* __restrict__ a) {
  const size_t idx = ((size_t)blockIdx.x * 256 + threadIdx.x) * 8;
  const float4 v0 = *(const float4*)&x[idx];
  const float4 v1 = *(const float4*)&x[idx + 4];
  const float f[8] = {v0.x, v0.y, v0.z, v0.w, v1.x, v1.y, v1.z, v1.w};
  u16x8 o;
  #pragma unroll
  for (int e = 0; e < 8; e++) o[e] = f2bf(f[e]);
  *(u16x8*)&a[idx] = o;
}

// ---------------- 256x256 8-phase bf16 GEMM (T1+T2+T3+T4+T5) ----------------
// C[M][N] = A[M][K] @ BT[N][KB]^T (+bias), with B K-tiles wrapped mod KB/64.
#define GPHASE(Q, STG, VMW)                                                        \
  {                                                                                \
    const int ab = arow + (Q) * 2048;                                              \
    bfrag8 a00 = *(const bfrag8*)&lds[b][0][ab + cA0];                             \
    bfrag8 a01 = *(const bfrag8*)&lds[b][0][ab + cA1];                             \
    bfrag8 a10 = *(const bfrag8*)&lds[b][0][ab + 1024 + cA0];                      \
    bfrag8 a11 = *(const bfrag8*)&lds[b][0][ab + 1024 + cA1];                      \
    if ((Q) == 0) {                                                                \
      _Pragma("unroll")                                                            \
      for (int j = 0; j < 4; j++) {                                                \
        bfr[j][0] = *(const bfrag8*)&lds[b][1][brow + j * 1024 + cA0];             \
        bfr[j][1] = *(const bfrag8*)&lds[b][1][brow + j * 1024 + cA1];             \
      }                                                                            \
    }                                                                              \
    STG;                                                                           \
    __builtin_amdgcn_s_barrier();                                                  \
    __builtin_amdgcn_s_setprio(1);                                                 \
    _Pragma("unroll")                                                              \
    for (int j = 0; j < 4; j++) {                                                  \
      acc[(Q)*2][j]   = __builtin_amdgcn_mfma_f32_16x16x32_bf16(a00, bfr[j][0], acc[(Q)*2][j], 0, 0, 0);   \
      acc[(Q)*2][j]   = __builtin_amdgcn_mfma_f32_16x16x32_bf16(a01, bfr[j][1], acc[(Q)*2][j], 0, 0, 0);   \
      acc[(Q)*2+1][j] = __builtin_amdgcn_mfma_f32_16x16x32_bf16(a10, bfr[j][0], acc[(Q)*2+1][j], 0, 0, 0); \
      acc[(Q)*2+1][j] = __builtin_amdgcn_mfma_f32_16x16x32_bf16(a11, bfr[j][1], acc[(Q)*2+1][j], 0, 0, 0); \
    }                                                                              \
    __builtin_amdgcn_s_setprio(0);                                                 \
    asm volatile("s_waitcnt lgkmcnt(0)" ::: "memory");                             \
    VMW;                                                                           \
    __builtin_amdgcn_s_barrier();                                                  \
  }

template<bool BIAS, typename OutT>
__global__ __launch_bounds__(512, 2)
void gemm256(const unsigned short* __restrict__ A,
             const unsigned short* __restrict__ BT,
             const float* __restrict__ bias, OutT* __restrict__ C,
             int M, int N, int K, int KB) {
  __shared__ alignas(16) unsigned short lds[2][2][256 * 64];
  const int tid = threadIdx.x;
  const int w = tid >> 6, lane = tid & 63;
  const int wm = w >> 2, wn = w & 3;            // 2 x 4 waves
  const int lq = lane >> 4, lr = lane & 15;

  const int nbx = N >> 8;
  const int cpx = (int)gridDim.x >> 3;
  const int bid = (int)blockIdx.x;
  const int swz = (bid & 7) * cpx + (bid >> 3);
  const int m0 = (swz / nbx) << 8;
  const int n0 = (swz % nbx) << 8;
  const int nkt = K >> 6;
  const int mskB = (KB >> 6) - 1;               // power-of-two tile counts only

  const int sr = tid >> 3;
  const int sc = ((tid & 7) ^ (sr & 7)) << 3;
  const unsigned short* gA = A + (size_t)(m0 + sr) * K + sc;
  const unsigned short* gB = BT + (size_t)(n0 + sr) * KB + sc;

  const int swl = (lr & 7) << 3;
  const int cA0 = (lq * 8) ^ swl;
  const int cA1 = (32 + lq * 8) ^ swl;
  const int arow = (wm * 128 + lr) * 64;
  const int brow = (wn * 64 + lr) * 64;

  ffrag4 acc[8][4] = {};
  bfrag8 bfr[4][2];

  auto stage = [&](int bb, int mat, int h, int kt) {
    const int kk = mat ? (kt & mskB) : kt;
    const int str = mat ? KB : K;
    const unsigned short* g = (mat ? gB : gA) + (size_t)(h * 128) * str + (size_t)kk * 64;
    unsigned short* l = &lds[bb][mat][h * 8192 + tid * 8];
    gload16(g, l);
    gload16(g + (size_t)64 * str, l + 4096);
  };

  stage(0, 0, 0, 0); stage(0, 0, 1, 0);
  stage(0, 1, 0, 0); stage(0, 1, 1, 0);
  stage(1, 1, 0, 1); stage(1, 1, 1, 1);
  asm volatile("s_waitcnt vmcnt(4)" ::: "memory");
  __builtin_amdgcn_s_barrier();

  for (int t = 0; t < nkt; ++t) {
    const int b = t & 1;
    const int bn = b ^ 1;
    GPHASE(0, { if (t + 1 < nkt) stage(bn, 0, 0, t + 1); }, {})
    GPHASE(1, { if (t + 1 < nkt) stage(bn, 0, 1, t + 1); }, {})
    GPHASE(2, { if (t + 2 < nkt) stage(b, 1, 0, t + 2); }, {})
    GPHASE(3, { if (t + 2 < nkt) stage(b, 1, 1, t + 2); },
           { if (t < nkt - 2) { asm volatile("s_waitcnt vmcnt(4)" ::: "memory"); }
             else             { asm volatile("s_waitcnt vmcnt(0)" ::: "memory"); } })
  }

  #pragma unroll
  for (int i = 0; i < 8; i++) {
    const int row = m0 + wm * 128 + i * 16 + lq * 4;
    #pragma unroll
    for (int j = 0; j < 4; j++) {
      const int col = n0 + wn * 64 + j * 16 + lr;
      const float bb = BIAS ? bias[col] : 0.f;
      #pragma unroll
      for (int r = 0; r < 4; r++) {
        const float val = acc[i][j][r] + bb;
        if constexpr (sizeof(OutT) == 2) C[(size_t)(row + r) * N + col] = (OutT)f2bf(val);
        else                             C[(size_t)(row + r) * N + col] = (OutT)val;
      }
    }
  }
}

// ---------- Stage A: MFMA k-feature + partial kv/ksum ----------
// V^T column-swizzle + V prefetch ping-pong + hoisted K loads; R9: setprio (T5).
__global__ __launch_bounds__(256, 2)
void kv_mfma_kernel(const unsigned short* __restrict__ qkv,
                    const unsigned short* __restrict__ projT,  // [H][256f][64d] bf16
                    float* __restrict__ partial) {
  const int c = blockIdx.x, bh = blockIdx.y;
  const int b = bh >> 4, h = bh & 15;
  const int tid = threadIdx.x;
  const int w = tid >> 6, lane = tid & 63;
  const int lq = lane >> 4, lr = lane & 15;
  __shared__ unsigned short kp[256 * 72];   // k'  [f][t], stride 72
  __shared__ unsigned short vT[80 * 72];    // V^T [d][t] col-swizzled, stride 72
  __shared__ float wmax[64][4];

  const unsigned short* pTg = projT + (size_t)h * (NF * HD);
  bfrag8 bfgP[2][4];
  #pragma unroll
  for (int kc = 0; kc < 2; kc++)
    #pragma unroll
    for (int j = 0; j < 4; j++)
      bfgP[kc][j] = *(const bfrag8*)&pTg[(size_t)(w * 64 + j * 16 + lr) * 64 + kc * 32 + lq * 8];

  for (int idx = tid; idx < 16 * 72; idx += 256) {
    const int r = idx / 72, cc = idx % 72;
    vT[(64 + r) * 72 + cc] = (r == 0 && cc < 64) ? (unsigned short)0x3F80 : (unsigned short)0;
  }
  __syncthreads();

  ffrag4 acc2[4][5];
  #pragma unroll
  for (int i = 0; i < 4; i++)
    #pragma unroll
    for (int j = 0; j < 5; j++) acc2[i][j] = (ffrag4){0.f, 0.f, 0.f, 0.f};

  const size_t rowbase = (size_t)b * TSEQ + (size_t)c * CH_T;
  const int vd0 = (tid & 7) * 8;
  const int vsg = tid & 7;
  const int vt0 = tid >> 3;

  auto loadV = [&](int tt, u16x8 (&vr)[2]) {
    #pragma unroll
    for (int e = 0; e < 2; e++) {
      const int t = e * 32 + vt0;
      vr[e] = *(const u16x8*)&qkv[(rowbase + tt * 64 + t) * QKV_N + 2048 + h * 64 + vd0];
    }
  };

  auto subtile = [&](int tt, u16x8 (&vcur)[2], u16x8 (&vnxt)[2], bool pf) {
    const int t0 = tt * 64;
    // issue K A-fragment loads FIRST (latency overlaps vT writes + Z start)
    bfrag8 af[2][4];
    #pragma unroll
    for (int kc = 0; kc < 2; kc++)
      #pragma unroll
      for (int i = 0; i < 4; i++)
        af[kc][i] = *(const bfrag8*)&qkv[(rowbase + t0 + i * 16 + lr) * QKV_N + 1024 + h * 64 + kc * 32 + lq * 8];
    #pragma unroll
    for (int e = 0; e < 2; e++) {
      const int scol = ((e * 32 + vt0) + 8 * vsg) & 63;
      #pragma unroll
      for (int q = 0; q < 8; q++) vT[(vd0 + q) * 72 + scol] = vcur[e][q];
    }
    ffrag4 accZ[4][4];
    #pragma unroll
    for (int i = 0; i < 4; i++)
      #pragma unroll
      for (int j = 0; j < 4; j++) accZ[i][j] = (ffrag4){0.f, 0.f, 0.f, 0.f};
    __builtin_amdgcn_s_setprio(1);
    #pragma unroll
    for (int kc = 0; kc < 2; kc++)
      #pragma unroll
      for (int i = 0; i < 4; i++)
        #pragma unroll
        for (int j = 0; j < 4; j++)
          accZ[i][j] = __builtin_amdgcn_mfma_f32_16x16x32_bf16(af[kc][i], bfgP[kc][j], accZ[i][j], 0, 0, 0);
    __builtin_amdgcn_s_setprio(0);
    float pmx[4][4];
    #pragma unroll
    for (int i = 0; i < 4; i++)
      #pragma unroll
      for (int r = 0; r < 4; r++) {
        float m = accZ[i][0][r];
        m = fmaxf(m, accZ[i][1][r]); m = fmaxf(m, accZ[i][2][r]); m = fmaxf(m, accZ[i][3][r]);
        pmx[i][r] = m;
      }
    #pragma unroll
    for (int off = 1; off < 16; off <<= 1)
      #pragma unroll
      for (int i = 0; i < 4; i++)
        #pragma unroll
        for (int r = 0; r < 4; r++)
          pmx[i][r] = fmaxf(pmx[i][r], __shfl_xor(pmx[i][r], off, 64));
    if (lr == 0)
      #pragma unroll
      for (int i = 0; i < 4; i++)
        #pragma unroll
        for (int r = 0; r < 4; r++) wmax[i * 16 + lq * 4 + r][w] = pmx[i][r];
    __syncthreads();                               // (1) wmax + vT ready
    #pragma unroll
    for (int i = 0; i < 4; i++) {
      float rmarr[4];
      #pragma unroll
      for (int r = 0; r < 4; r++) {
        const float4 wv = *(const float4*)&wmax[i * 16 + lq * 4 + r];
        rmarr[r] = fmaxf(fmaxf(wv.x, wv.y), fmaxf(wv.z, wv.w));
      }
      #pragma unroll
      for (int j = 0; j < 4; j++) {
        u16x4 pk;
        #pragma unroll
        for (int r = 0; r < 4; r++) pk[r] = f2bf(__expf(accZ[i][j][r] - rmarr[r]));
        *(u16x4*)&kp[(w * 64 + j * 16 + lr) * 72 + i * 16 + lq * 4] = pk;
      }
    }
    if (pf) loadV(tt + 1, vnxt);                   // T14: hide under KV phase
    __syncthreads();                               // (2) kp ready
    #pragma unroll
    for (int kc = 0; kc < 2; kc++) {
      bfrag8 af2[4], bf2[5];
      #pragma unroll
      for (int i = 0; i < 4; i++)
        af2[i] = *(const bfrag8*)&kp[(w * 64 + i * 16 + lr) * 72 + kc * 32 + lq * 8];
      #pragma unroll
      for (int j = 0; j < 5; j++) {
        const int vrow = j * 16 + lr;
        const int vcol = ((kc * 32 + lq * 8) + 8 * ((2 * j + (lr >> 3)) & 7)) & 63;
        bf2[j] = *(const bfrag8*)&vT[vrow * 72 + vcol];
      }
      __builtin_amdgcn_s_setprio(1);
      #pragma unroll
      for (int i = 0; i < 4; i++)
        #pragma unroll
        for (int j = 0; j < 5; j++)
          acc2[i][j] = __builtin_amdgcn_mfma_f32_16x16x32_bf16(af2[i], bf2[j], acc2[i][j], 0, 0, 0);
      __builtin_amdgcn_s_setprio(0);
    }
    __syncthreads();                               // (3) protect kp/vT
  };

  u16x8 vA[2], vB[2];
  loadV(0, vA);
  for (int uu = 0; uu < CH_T / 64; uu += 2) {
    subtile(uu,     vA, vB, true);
    subtile(uu + 1, vB, vA, uu + 2 < CH_T / 64);
  }

  float* pbase = partial + (size_t)(bh * NCHUNK + c) * NF * KVS;
  #pragma unroll
  for (int i = 0; i < 4; i++)
    #pragma unroll
    for (int j = 0; j < 5; j++) {
      if (j == 4 && lr != 0) continue;
      const int col = j * 16 + lr;
      #pragma unroll
      for (int r = 0; r < 4; r++)
        pbase[(size_t)(w * 64 + i * 16 + lq * 4 + r) * KVS + col] = acc2[i][j][r];
    }
}

// ---------------- reduce kv partials over 8 chunks ----------------
__global__ __launch_bounds__(256)
void kv_reduce_kernel(const float* __restrict__ partial, float* __restrict__ kv) {
  const size_t i = (size_t)blockIdx.x * 256 + threadIdx.x;
  const size_t per_bh = (size_t)NF * KVS;
  const size_t bh = i / per_bh;
  const size_t j = i % per_bh;
  const float* p = partial + bh * NCHUNK * per_bh + j;
  float s = 0.f;
  #pragma unroll
  for (int c = 0; c < NCHUNK; c++) s += p[c * per_bh];
  kv[i] = s;
}

// ---------- Stage B: MFMA q-feature + O = q' @ [KV | ksum] + normalize ----------
// Q-fragment prefetch ping-pong; no Q-side max; R9: setprio (T5).
__global__ __launch_bounds__(256, 2)
void q_attn_mfma_kernel(const unsigned short* __restrict__ qkv,
                        const unsigned short* __restrict__ projT,
                        const float* __restrict__ kv,
                        unsigned short* __restrict__ attn) {
  const int c = blockIdx.x, bh = blockIdx.y;
  const int b = bh >> 4, h = bh & 15;
  const int tid = threadIdx.x;
  const int w = tid >> 6, lane = tid & 63;
  const int lq = lane >> 4, lr = lane & 15;
  __shared__ unsigned short qp[64 * 264];    // q' [t][f], stride 264
  __shared__ unsigned short kvT[80 * 264];   // KV^T [d][f] (+ksum row 64)

  {
    const float* kvrow = kv + ((size_t)bh * NF + tid) * KVS;
    #pragma unroll
    for (int d0 = 0; d0 < 64; d0 += 4) {
      const float4 v = *(const float4*)&kvrow[d0];
      kvT[(d0 + 0) * 264 + tid] = f2bf(v.x);
      kvT[(d0 + 1) * 264 + tid] = f2bf(v.y);
      kvT[(d0 + 2) * 264 + tid] = f2bf(v.z);
      kvT[(d0 + 3) * 264 + tid] = f2bf(v.w);
    }
    kvT[64 * 264 + tid] = f2bf(kvrow[64]);
    for (int idx = tid; idx < 15 * 264; idx += 256)
      kvT[65 * 264 + idx] = 0;
  }
  const unsigned short* pTg = projT + (size_t)h * (NF * HD);
  bfrag8 bfg[2][4];
  #pragma unroll
  for (int kc = 0; kc < 2; kc++)
    #pragma unroll
    for (int j = 0; j < 4; j++)
      bfg[kc][j] = *(const bfrag8*)&pTg[(size_t)(w * 64 + j * 16 + lr) * 64 + kc * 32 + lq * 8];
  __syncthreads();

  auto loadQ = [&](int tt, bfrag8 (&af)[2][4]) {
    const size_t rowb = (size_t)b * TSEQ + (size_t)c * CH_T + (size_t)tt * 64;
    #pragma unroll
    for (int kc = 0; kc < 2; kc++)
      #pragma unroll
      for (int i = 0; i < 4; i++)
        af[kc][i] = *(const bfrag8*)&qkv[(rowb + i * 16 + lr) * QKV_N + 0 + h * 64 + kc * 32 + lq * 8];
  };

  auto subtile = [&](int tt, bfrag8 (&cur)[2][4], bfrag8 (&nxt)[2][4], bool pf) {
    ffrag4 accZ[4][4];
    #pragma unroll
    for (int i = 0; i < 4; i++)
      #pragma unroll
      for (int j = 0; j < 4; j++) accZ[i][j] = (ffrag4){0.f, 0.f, 0.f, 0.f};
    __builtin_amdgcn_s_setprio(1);
    #pragma unroll
    for (int kc = 0; kc < 2; kc++)
      #pragma unroll
      for (int i = 0; i < 4; i++)
        #pragma unroll
        for (int j = 0; j < 4; j++)
          accZ[i][j] = __builtin_amdgcn_mfma_f32_16x16x32_bf16(cur[kc][i], bfg[kc][j], accZ[i][j], 0, 0, 0);
    __builtin_amdgcn_s_setprio(0);
    #pragma unroll
    for (int i = 0; i < 4; i++)
      #pragma unroll
      for (int j = 0; j < 4; j++)
        #pragma unroll
        for (int r = 0; r < 4; r++)
          qp[(i * 16 + lq * 4 + r) * 264 + w * 64 + j * 16 + lr] = f2bf(__expf(accZ[i][j][r]));
    if (pf) loadQ(tt + 1, nxt);                    // T14: hide under PV phase
    __syncthreads();
    ffrag4 acc3[5];
    #pragma unroll
    for (int j = 0; j < 5; j++) acc3[j] = (ffrag4){0.f, 0.f, 0.f, 0.f};
    #pragma unroll
    for (int kc = 0; kc < 8; kc++) {
      const bfrag8 afq = *(const bfrag8*)&qp[(w * 16 + lr) * 264 + kc * 32 + lq * 8];
      __builtin_amdgcn_s_setprio(1);
      #pragma unroll
      for (int j = 0; j < 5; j++) {
        const bfrag8 bf3 = *(const bfrag8*)&kvT[(j * 16 + lr) * 264 + kc * 32 + lq * 8];
        acc3[j] = __builtin_amdgcn_mfma_f32_16x16x32_bf16(afq, bf3, acc3[j], 0, 0, 0);
      }
      __builtin_amdgcn_s_setprio(0);
    }
    #pragma unroll
    for (int r = 0; r < 4; r++) {
      const float den = __shfl(acc3[4][r], lane & 48, 64);
      const float z = 1.f / (den + 1e-6f);
      const int t = c * CH_T + tt * 64 + w * 16 + lq * 4 + r;
      unsigned short* orow = attn + ((size_t)b * TSEQ + t) * DIM_ + h * 64;
      #pragma unroll
      for (int j = 0; j < 4; j++)
        orow[j * 16 + lr] = f2bf(acc3[j][r] * z);
    }
    __syncthreads();
  };

  bfrag8 qA[2][4], qB[2][4];
  loadQ(0, qA);
  for (int uu = 0; uu < CH_T / 64; uu += 2) {
    subtile(uu,     qA, qB, true);
    subtile(uu + 1, qB, qA, uu + 2 < CH_T / 64);
  }
}

extern "C" void kernel_launch(void* const* d_in, const int* in_sizes, int n_in,
                              void* d_out, int out_size, void* d_ws, size_t ws_size,
                              hipStream_t stream) {
  const float* x     = (const float*)d_in[0];
  const float* w_qkv = (const float*)d_in[1];
  const float* w_out = (const float*)d_in[2];
  const float* b_out = (const float*)d_in[3];
  const float* proj  = (const float*)d_in[4];
  float* out = (float*)d_out;

  char* ws = (char*)d_ws;
  // Workspace layout (max 141,295,616 B):
  //   [0,          100663296)  qkv bf16 (16384*3072)
  //   phase 1:
  //     [100663296, 134217728)  a2 bf16 (16384*1024)  x cast to bf16
  //     [134217728, 140509184)  wqkvT bf16 (3072*1024)
  //   phase 2 (a2/wqkvT dead after qkv GEMM):
  //     [100663296, 136314880)  partial fp32 (64*8*256*68)   — then:
  //     [100663296, 134217728)  attn bf16 (16384*1024)
  //     [134217728, 136314880)  woutT bf16 (1024*1024)
  //     [136314880, 140771328)  kv fp32 (64*256*68)
  //   [140771328, 141295616)  projT bf16 — alive throughout
  unsigned short* qkv    = (unsigned short*)ws;
  unsigned short* a2     = (unsigned short*)(ws + 100663296);
  unsigned short* wqkvT  = (unsigned short*)(ws + 134217728);
  float*          partial= (float*)(ws + 100663296);
  unsigned short* attn   = (unsigned short*)(ws + 100663296);
  unsigned short* woutT  = (unsigned short*)(ws + 134217728);
  float*          kvbuf  = (float*)(ws + 136314880);
  unsigned short* projT  = (unsigned short*)(ws + 140771328);

  transpose_cast<<<dim3(QKV_N/32, DIM_/32, 1), 256, 0, stream>>>(w_qkv, wqkvT, DIM_, QKV_N);
  transpose_cast<<<dim3(NF/32, HD/32, NH), 256, 0, stream>>>(proj, projT, HD, NF);

  // 1) qkv = x @ w_qkv — plain bf16 K=1024 GEMM (R7 configuration, CVT reverted)
  bf16_cast<<<8192, 256, 0, stream>>>(x, a2);
  gemm256<false, unsigned short><<<768, 512, 0, stream>>>(
      a2, wqkvT, nullptr, qkv, TOK, QKV_N, 1024, 1024);
  // 2) MFMA k-feature + partial kv/ksum
  kv_mfma_kernel<<<dim3(NCHUNK, 64), 256, 0, stream>>>(qkv, projT, partial);
  // 3) reduce partials
  kv_reduce_kernel<<<dim3(64*NF*KVS/256), 256, 0, stream>>>(partial, kvbuf);
  // 4) woutT (into region freed by reduce)
  transpose_cast<<<dim3(DIM_/32, DIM_/32, 1), 256, 0, stream>>>(w_out, woutT, DIM_, DIM_);
  // 5) MFMA q-feature + q'@kv + normalize -> attn bf16
  q_attn_mfma_kernel<<<dim3(NCHUNK, 64), 256, 0, stream>>>(qkv, projT, kvbuf, attn);
  // 6) out = attn @ w_out + b_out
  gemm256<true, float><<<256, 512, 0, stream>>>(attn, woutT, b_out, out, TOK, DIM_, DIM_, DIM_);
}